// Round 4
// baseline (25013.133 us; speedup 1.0000x reference)
//
#include <hip/hip_runtime.h>
#include <hip/hip_bf16.h>
#include <cstdint>

#define L_SEQ 8192
#define EMB   2048
#define HID   2048
#define N3H   6144

typedef __attribute__((ext_vector_type(8))) short short8;
typedef __attribute__((ext_vector_type(4))) float f32x4;
typedef __attribute__((ext_vector_type(4))) unsigned int uintx4;

__device__ __forceinline__ unsigned short f2bf(float f) {
    union { float f; unsigned int u; } v; v.f = f;
    unsigned int u = v.u;
    unsigned int lsb = (u >> 16) & 1u;
    u += 0x7fffu + lsb;                 // round-to-nearest-even
    return (unsigned short)(u >> 16);
}

__device__ __forceinline__ float bf2f(unsigned int s) {
    union { unsigned int u; float f; } v;
    v.u = (s & 0xffffu) << 16;
    return v.f;
}

// 16-B / 4-B uncached (MALL-coherent) accesses: sc0 sc1 bypass L1+L2
__device__ __forceinline__ uintx4 ld16(const uintx4* p) {
    uintx4 r;
    asm volatile("global_load_dwordx4 %0, %1, off sc0 sc1\n\ts_waitcnt vmcnt(0)"
                 : "=v"(r) : "v"(p) : "memory");
    return r;
}
__device__ __forceinline__ void st16(uintx4* p, uintx4 v) {
    asm volatile("global_store_dwordx4 %0, %1, off sc0 sc1"
                 :: "v"(p), "v"(v) : "memory");
}
__device__ __forceinline__ void st4(unsigned int* p, unsigned int v) {
    asm volatile("global_store_dword %0, %1, off sc0 sc1"
                 :: "v"(p), "v"(v) : "memory");
}

// ---------------------------------------------------------------- fp32 -> bf16
__global__ void cvt_f32_bf16(const float* __restrict__ src,
                             unsigned short* __restrict__ dst, int n) {
    int i = (blockIdx.x * blockDim.x + threadIdx.x) * 4;
    if (i < n) {
        float4 v = *(const float4*)(src + i);
        ushort4 o;
        o.x = f2bf(v.x); o.y = f2bf(v.y); o.z = f2bf(v.z); o.w = f2bf(v.w);
        *(ushort4*)(dst + i) = o;
    }
}

// ---------------------------------------------------------------- GI = X @ W_ih^T + b_ih  (bf16 MFMA, out bf16)
__global__ __launch_bounds__(256) void gemm_gi(const unsigned short* __restrict__ Xb,
                                               const unsigned short* __restrict__ Wb,
                                               const float* __restrict__ bih,
                                               unsigned short* __restrict__ GIb) {
    __shared__ unsigned short As[128][40];
    __shared__ unsigned short Bs[128][40];
    const int tid = threadIdx.x;
    const int wid = tid >> 6, l = tid & 63;
    const int q = l >> 4, r16 = l & 15;
    const int bm = blockIdx.y, bn = blockIdx.x;
    const int wm = (wid >> 1) * 64, wn = (wid & 1) * 64;

    f32x4 acc[4][4] = {};

    const int srow = tid >> 1, sseg = (tid & 1) * 16;
    const unsigned short* xsrc = Xb + (size_t)(bm * 128 + srow) * 2048 + sseg;
    const unsigned short* wsrc = Wb + (size_t)(bn * 128 + srow) * 2048 + sseg;

    for (int k0 = 0; k0 < 2048; k0 += 32) {
        __syncthreads();
        uint4 va0 = *(const uint4*)(xsrc + k0);
        uint4 va1 = *(const uint4*)(xsrc + k0 + 8);
        uint4 vb0 = *(const uint4*)(wsrc + k0);
        uint4 vb1 = *(const uint4*)(wsrc + k0 + 8);
        *(uint4*)&As[srow][sseg]     = va0;
        *(uint4*)&As[srow][sseg + 8] = va1;
        *(uint4*)&Bs[srow][sseg]     = vb0;
        *(uint4*)&Bs[srow][sseg + 8] = vb1;
        __syncthreads();

        short8 af[4], bfr[4];
#pragma unroll
        for (int i = 0; i < 4; i++) af[i]  = *(const short8*)&As[wm + 16 * i + r16][q * 8];
#pragma unroll
        for (int j = 0; j < 4; j++) bfr[j] = *(const short8*)&Bs[wn + 16 * j + r16][q * 8];
#pragma unroll
        for (int i = 0; i < 4; i++)
#pragma unroll
            for (int j = 0; j < 4; j++)
                acc[i][j] = __builtin_amdgcn_mfma_f32_16x16x32_bf16(af[i], bfr[j], acc[i][j], 0, 0, 0);
    }

#pragma unroll
    for (int j = 0; j < 4; j++) {
        int n = bn * 128 + wn + 16 * j + r16;
        float bias = bih[n];
#pragma unroll
        for (int i = 0; i < 4; i++) {
            int mbase = bm * 128 + wm + 16 * i + q * 4;
#pragma unroll
            for (int p = 0; p < 4; p++) {
                GIb[(size_t)(mbase + p) * N3H + n] = f2bf(acc[i][j][p] + bias);
            }
        }
    }
}

// ---------------------------------------------------------------- persistent GRU scan
// 256 blocks x 512 threads; block b owns h[8b..8b+8), wave w owns the (r,z,n)
// triple for hidx=8b+w; Whh rows fp32 in registers (96 VGPR/lane) — requires
// __launch_bounds__(512,1): the (512,2) cap of 128 VGPRs demoted the weights
// in R3 (VGPR_Count=68 -> per-step weight re-reads; FETCH_SIZE showed it).
//
// Ordered two-level publish (fixes R3's signal/payload race):
//  - payload: rec[(t+1)&1][2b+s], 16 B = {4 bf16 | tag32=t+1 | 0}, sc0sc1
//  - s_waitcnt vmcnt(0)   <- payload durable at MALL BEFORE signal
//  - signal:  tags[(t+1)&1][b] = t+1 (4-B sc0sc1 store, packed 1-KB array)
//  - consume: wave0 polls all 256 tags coalesced (64 lanes x dwordx4 = 1 KB
//    per round, no RMW serialization); tag==t observed => payload landed =>
//    single ld16, verify-retry never fires. Parity overwrite safety as R3.
//  - poison 0xAAAAAAAA never matches tags t in [1,8192]: no memset needed.
__global__ __launch_bounds__(512, 1) void gru_scan(const float* __restrict__ Whh,
                                                   const float* __restrict__ bhh,
                                                   const unsigned short* __restrict__ GIb,
                                                   uintx4* rec,            // [2][512]
                                                   unsigned int* tags) {   // [2][256]
    __shared__ float h_lds[2][2048];
    __shared__ float hnew_lds[8];
    const int tid = threadIdx.x;
    const int w = tid >> 6, l = tid & 63;
    const int b = blockIdx.x;
    const int hidx = b * 8 + w;

    // weights: 3 rows (r,z,n) for hidx, fp32 in registers
    float4 wreg[3][8];
    float bb[3];
#pragma unroll
    for (int g = 0; g < 3; g++) {
        int r = g * HID + hidx;
        bb[g] = bhh[r];
        const float* wr = Whh + (size_t)r * HID + 4 * l;
#pragma unroll
        for (int i = 0; i < 8; i++) wreg[g][i] = *(const float4*)(wr + 256 * i);
    }

    {
        float4 z4 = {0.f, 0.f, 0.f, 0.f};
        *(float4*)&h_lds[0][tid * 4] = z4;
    }
    __syncthreads();

    // GI(0) prefetch (wave-uniform address -> one fetch, broadcast)
    unsigned short gr = GIb[hidx];
    unsigned short gz = GIb[2048 + hidx];
    unsigned short gn = GIb[4096 + hidx];

    for (int t = 0; t < L_SEQ; t++) {
        const int p = t & 1;

        // prefetch GI(t+1): consumed at end of step t+1 -> ~1 full step of slack
        unsigned short gr2 = 0, gz2 = 0, gn2 = 0;
        if (t + 1 < L_SEQ) {
            const unsigned short* gq = GIb + (size_t)(t + 1) * N3H + hidx;
            gr2 = gq[0]; gz2 = gq[2048]; gn2 = gq[4096];
        }

        if (t > 0) {
            // 1) wave0: coalesced poll of the whole 1-KB tag array
            if (w == 0) {
                const uintx4* tp = (const uintx4*)(tags + (size_t)p * 256) + l;
                const unsigned int tg = (unsigned int)t;
                while (1) {
                    uintx4 tv = ld16(tp);
                    int ok = (tv.x == tg) & (tv.y == tg) & (tv.z == tg) & (tv.w == tg);
                    if (__all(ok)) break;
                }
            }
            __syncthreads();

            // 2) bulk payload read ONCE (tag observed => landed; retry is dead code)
            const uintx4* rp = rec + (size_t)p * 512 + tid;
            uintx4 rv = ld16(rp);
            while (rv.z != (unsigned int)t) rv = ld16(rp);
            float4 hv;
            hv.x = bf2f(rv.x);
            hv.y = bf2f(rv.x >> 16);
            hv.z = bf2f(rv.y);
            hv.w = bf2f(rv.y >> 16);
            *(float4*)&h_lds[p][4 * tid] = hv;
        }
        __syncthreads();

        float hprev = h_lds[p][hidx];

        float a0 = 0.f, a1 = 0.f, a2 = 0.f;
#pragma unroll
        for (int i = 0; i < 8; i++) {
            float4 hv = *(const float4*)&h_lds[p][4 * l + 256 * i];
            a0 = fmaf(wreg[0][i].x, hv.x, a0); a0 = fmaf(wreg[0][i].y, hv.y, a0);
            a0 = fmaf(wreg[0][i].z, hv.z, a0); a0 = fmaf(wreg[0][i].w, hv.w, a0);
            a1 = fmaf(wreg[1][i].x, hv.x, a1); a1 = fmaf(wreg[1][i].y, hv.y, a1);
            a1 = fmaf(wreg[1][i].z, hv.z, a1); a1 = fmaf(wreg[1][i].w, hv.w, a1);
            a2 = fmaf(wreg[2][i].x, hv.x, a2); a2 = fmaf(wreg[2][i].y, hv.y, a2);
            a2 = fmaf(wreg[2][i].z, hv.z, a2); a2 = fmaf(wreg[2][i].w, hv.w, a2);
        }
        a0 += __shfl_xor(a0, 32); a1 += __shfl_xor(a1, 32); a2 += __shfl_xor(a2, 32);
        a0 += __shfl_xor(a0, 16); a1 += __shfl_xor(a1, 16); a2 += __shfl_xor(a2, 16);
        a0 += __shfl_xor(a0, 8);  a1 += __shfl_xor(a1, 8);  a2 += __shfl_xor(a2, 8);
        a0 += __shfl_xor(a0, 4);  a1 += __shfl_xor(a1, 4);  a2 += __shfl_xor(a2, 4);
        a0 += __shfl_xor(a0, 2);  a1 += __shfl_xor(a1, 2);  a2 += __shfl_xor(a2, 2);
        a0 += __shfl_xor(a0, 1);  a1 += __shfl_xor(a1, 1);  a2 += __shfl_xor(a2, 1);

        if (l == 0) {
            float r  = 1.f / (1.f + __expf(-(bf2f(gr) + a0 + bb[0])));
            float z  = 1.f / (1.f + __expf(-(bf2f(gz) + a1 + bb[1])));
            float hn = a2 + bb[2];
            float xn = bf2f(gn) + r * hn;
            xn = fminf(fmaxf(xn, -15.f), 15.f);
            float e  = __expf(2.f * xn);
            float nn = (e - 1.f) / (e + 1.f);
            hnew_lds[w] = z * hprev + (1.f - z) * nn;
        }
        __syncthreads();

        // ordered publish: payload -> vmcnt(0) -> tag
        if (w == 0) {
            if (l < 2) {
                const float* hp = hnew_lds + 4 * l;
                unsigned int w0 = (unsigned int)f2bf(hp[0]) | ((unsigned int)f2bf(hp[1]) << 16);
                unsigned int w1 = (unsigned int)f2bf(hp[2]) | ((unsigned int)f2bf(hp[3]) << 16);
                uintx4 pk;
                pk.x = w0; pk.y = w1; pk.z = (unsigned int)(t + 1); pk.w = 0u;
                st16(rec + (size_t)((t + 1) & 1) * 512 + 2 * b + l, pk);
            }
            asm volatile("s_waitcnt vmcnt(0)" ::: "memory");
            if (l == 0)
                st4(tags + (size_t)((t + 1) & 1) * 256 + b, (unsigned int)(t + 1));
        }

        gr = gr2; gz = gz2; gn = gn2;
    }
}

// ---------------------------------------------------------------- out = sigmoid(h . fc_w + fc_b)
// final h (tag 8192, parity 0) in rec[0][0..512): {4 bf16 | tag | pad}
__global__ void fc_out(const uintx4* __restrict__ rec,
                       const float* __restrict__ fw,
                       const float* __restrict__ fb, float* __restrict__ out) {
    __shared__ float red[8];
    const int tid = threadIdx.x;
    const int wid = tid >> 6, l = tid & 63;
    uintx4 rv = *(rec + tid);     // plain load: prior kernel completion = visible
    float4 wv = *(const float4*)&fw[4 * tid];
    float s = bf2f(rv.x) * wv.x + bf2f(rv.x >> 16) * wv.y +
              bf2f(rv.y) * wv.z + bf2f(rv.y >> 16) * wv.w;
    s += __shfl_xor(s, 32); s += __shfl_xor(s, 16); s += __shfl_xor(s, 8);
    s += __shfl_xor(s, 4);  s += __shfl_xor(s, 2);  s += __shfl_xor(s, 1);
    if (l == 0) red[wid] = s;
    __syncthreads();
    if (tid == 0) {
        float tot = 0.f;
#pragma unroll
        for (int i = 0; i < 8; i++) tot += red[i];
        tot += fb[0];
        out[0] = 1.f / (1.f + __expf(-tot));
    }
}

// ---------------------------------------------------------------- launch
extern "C" void kernel_launch(void* const* d_in, const int* in_sizes, int n_in,
                              void* d_out, int out_size, void* d_ws, size_t ws_size,
                              hipStream_t stream) {
    const float* x   = (const float*)d_in[0];
    const float* Wih = (const float*)d_in[1];
    const float* Whh = (const float*)d_in[2];
    const float* bih = (const float*)d_in[3];
    const float* bhh = (const float*)d_in[4];
    const float* fcw = (const float*)d_in[5];
    const float* fcb = (const float*)d_in[6];
    float* out = (float*)d_out;

    char* ws = (char*)d_ws;
    unsigned short* Xb  = (unsigned short*)ws;                         // 33,554,432 B
    unsigned short* Wb  = (unsigned short*)(ws + 33554432);            // 25,165,824 B
    unsigned short* GIb = (unsigned short*)(ws + 58720256);            // 100,663,296 B
    uintx4* rec         = (uintx4*)(ws + 159383552);                   // 16,384 B
    unsigned int* tags  = (unsigned int*)(ws + 159399936);             // 2,048 B

    cvt_f32_bf16<<<16384, 256, 0, stream>>>(x,   Xb, L_SEQ * EMB);
    cvt_f32_bf16<<<12288, 256, 0, stream>>>(Wih, Wb, N3H * EMB);

    dim3 gg(48, 64);
    gemm_gi<<<gg, 256, 0, stream>>>(Xb, Wb, bih, GIb);

    gru_scan<<<256, 512, 0, stream>>>(Whh, bhh, GIb, rec, tags);

    fc_out<<<1, 512, 0, stream>>>(rec, fcw, fcb, out);
}